// Round 12
// baseline (220.340 us; speedup 1.0000x reference)
//
#include <hip/hip_runtime.h>
#include <hip/hip_bf16.h>

// Causal attention B=2,H=12,S=2048,D=64 fp32 in/out.
// R12 = R11 with the dbuf<->residency trade flipped: single-buffered K/V
// (LDS 32 KB: Ks 8 + Vs 8 + Ps 16) -> 5 blocks/CU, and chunk=6 (1224 blocks,
// 4.8/CU) so the extra residency slots are actually fillable. 2 barriers/iter,
// but commit's vmcnt wait is for loads issued a full iter earlier (landed),
// and 5 resident blocks overlap each other's barrier stalls.
// R10/R11 lesson: chunk granularity trades tail idle vs partials traffic;
// at 3 blocks/CU finer chunks lose, at 5/CU cap they pay for themselves.
// Carried: XCD swizzle (3 heads/XCD), 1-iter prefetch into regs, bf16 partial
// O + f32 l, direct-out for single-chunk q-tiles (mt2<=2), BM=128, S^T=K*Q^T
// (packed b64 P stores), static-max base-2 softmax, XOR-swizzled packed LDS,
// Q read f32-direct (no Q prepass). R9 lesson stands: keep K=32 PV.

#define SEQ 2048
#define DH 64
#define NHEADS 24
#define BN 64
#define LDK 72
#define ELEMS_PER_TENSOR (NHEADS * SEQ * DH)          // 3145728
#define NSLOT12 (NHEADS * 16 * 6)                     // 2304
#define WS_KV    ((size_t)2 * ELEMS_PER_TENSOR * 2)   // 12582912 B
#define WS_FA12  (WS_KV + (size_t)NSLOT12 * 8192 * 2 + (size_t)NSLOT12 * 128 * 4)

typedef float f32x4 __attribute__((ext_vector_type(4)));
typedef __bf16 bf16x8 __attribute__((ext_vector_type(8)));
typedef __bf16 bf16x4 __attribute__((ext_vector_type(4)));

#if __has_builtin(__builtin_amdgcn_exp2f)
#define EXP2F(x) __builtin_amdgcn_exp2f(x)
#else
#define EXP2F(x) exp2f(x)
#endif

#define QSCALE 0.1803368801111204f   // log2(e)/8: folds 1/sqrt(64) + base-2

// ---------------- pre-pass: K -> bf16, V -> bf16 transposed ----------------
__global__ __launch_bounds__(256)
void prep_kernel(const float* __restrict__ k, const float* __restrict__ v,
                 __bf16* __restrict__ ks, __bf16* __restrict__ vt)
{
    __shared__ __bf16 T[64][LDK];
    const int bx = blockIdx.x;
    const int tid = threadIdx.x;
    if (bx < 1536) {                       // K bf16 convert
        const int idx = (bx * 256 + tid) * 8;
        f32x4 a = *(const f32x4*)(k + idx);
        f32x4 b = *(const f32x4*)(k + idx + 4);
        bf16x8 o;
        #pragma unroll
        for (int j = 0; j < 4; ++j) { o[j] = (__bf16)a[j]; o[4 + j] = (__bf16)b[j]; }
        *(bf16x8*)(ks + idx) = o;
    } else {                               // V transpose to [bh][d][s]
        const int b2 = bx - 1536;
        const int bh = b2 >> 5;
        const int s0 = (b2 & 31) * 64;
        const int r = tid >> 2, c0 = (tid & 3) * 16;
        const float* vp = v + (size_t)bh * SEQ * DH + (size_t)(s0 + r) * DH + c0;
        __bf16 tmp[16];
        #pragma unroll
        for (int jj = 0; jj < 16; ++jj) tmp[jj] = (__bf16)vp[jj];
        *(bf16x8*)&T[r][c0]     = *(bf16x8*)&tmp[0];
        *(bf16x8*)&T[r][c0 + 8] = *(bf16x8*)&tmp[8];
        __syncthreads();
        const int d = tid >> 2, j0 = (tid & 3) * 16;
        __bf16 o[16];
        #pragma unroll
        for (int jj = 0; jj < 16; ++jj) o[jj] = T[j0 + jj][d];
        __bf16* op = vt + (size_t)bh * DH * SEQ + (size_t)d * SEQ + s0 + j0;
        *(bf16x8*)op       = *(bf16x8*)&o[0];
        *(bf16x8*)(op + 8) = *(bf16x8*)&o[8];
    }
}

// ---------------- main: BM=128, split-K(6), single-buf, 5 blocks/CU ----------------
__global__ __launch_bounds__(256, 5)
void fa12_kernel(const float* __restrict__ q, const __bf16* __restrict__ ks,
                 const __bf16* __restrict__ vt,
                 __bf16* __restrict__ opart, float* __restrict__ lpart,
                 float* __restrict__ out)
{
    const int bx = blockIdx.x;             // 1224 = 8 XCDs x 3 headgrp x 51
    const int xcd = bx & 7;
    const int sub = bx >> 3;               // 0..152
    const int bh = (sub / 51) * 8 + xcd;   // 3 heads pinned per XCD
    const int i = sub % 51;                // low i = high mt2 = heavy-first
    int mt2, ch;
    if      (i < 6)  { mt2 = 15; ch = i; }
    else if (i < 11) { mt2 = 14; ch = i - 6; }
    else if (i < 16) { mt2 = 13; ch = i - 11; }
    else if (i < 21) { mt2 = 12; ch = i - 16; }
    else if (i < 25) { mt2 = 11; ch = i - 21; }
    else if (i < 29) { mt2 = 10; ch = i - 25; }
    else if (i < 33) { mt2 = 9;  ch = i - 29; }
    else if (i < 36) { mt2 = 8;  ch = i - 33; }
    else if (i < 39) { mt2 = 7;  ch = i - 36; }
    else if (i < 42) { mt2 = 6;  ch = i - 39; }
    else if (i < 44) { mt2 = 5;  ch = i - 42; }
    else if (i < 46) { mt2 = 4;  ch = i - 44; }
    else if (i < 48) { mt2 = 3;  ch = i - 46; }
    else if (i < 49) { mt2 = 2;  ch = 0; }
    else if (i < 50) { mt2 = 1;  ch = 0; }
    else             { mt2 = 0;  ch = 0; }
    const int jt0 = ch * 6;
    const int jt_end = min(jt0 + 6, 2 * mt2 + 2);
    const int q0 = mt2 * 128;

    const int tid = threadIdx.x;
    const int w = tid >> 6, lane = tid & 63;
    const int g = lane >> 4, li = lane & 15;

    __shared__ __bf16 Ks[64 * 64];         // 8 KB single-buffered
    __shared__ __bf16 Vs[64 * 64];         // 8 KB
    __shared__ __bf16 Ps[4 * 32 * 64];     // 16 KB per-wave P tiles

    const __bf16* kh = ks + (size_t)bh * SEQ * DH;
    const __bf16* vh = vt + (size_t)bh * DH * SEQ;   // [d][s]

    // Q fragments: direct f32 load, scale+pack (B-operand layout for S^T)
    bf16x8 qf[2][2];
    #pragma unroll
    for (int a = 0; a < 2; ++a) {
        const float* qp = q + (size_t)bh * SEQ * DH +
                          (size_t)(q0 + w * 32 + a * 16 + li) * DH + g * 8;
        #pragma unroll
        for (int c = 0; c < 2; ++c) {
            f32x4 x0 = *(const f32x4*)(qp + c * 32);
            f32x4 x1 = *(const f32x4*)(qp + c * 32 + 4);
            #pragma unroll
            for (int j = 0; j < 4; ++j) {
                qf[a][c][j]     = (__bf16)(x0[j] * QSCALE);
                qf[a][c][4 + j] = (__bf16)(x1[j] * QSCALE);
            }
        }
    }

    bf16x8 ones;
    #pragma unroll
    for (int j = 0; j < 8; ++j) ones[j] = (__bf16)1.0f;

    f32x4 acc[2][4] = {};
    f32x4 accl[2] = {};

    const int srow0 = tid >> 3;            // staging: + s*32
    const int sg    = tid & 7;

    bf16x8 kr[2], vr[2];
    // ---- prologue: tile jt0 -> LDS; issue loads for jt0+1 ----
    #pragma unroll
    for (int s = 0; s < 2; ++s) {
        const int row = s * 32 + srow0;
        const int lg = sg ^ (row & 7);
        kr[s] = *(const bf16x8*)(kh + (size_t)(jt0 * BN + row) * DH + lg * 8);
        vr[s] = *(const bf16x8*)(vh + (size_t)row * SEQ + jt0 * BN + lg * 8);
    }
    #pragma unroll
    for (int s = 0; s < 2; ++s) {
        *(bf16x8*)((char*)Ks + s * 4096 + tid * 16) = kr[s];
        *(bf16x8*)((char*)Vs + s * 4096 + tid * 16) = vr[s];
    }
    if (jt0 + 1 < jt_end) {
        const int kv1 = (jt0 + 1) * BN;
        #pragma unroll
        for (int s = 0; s < 2; ++s) {
            const int row = s * 32 + srow0;
            const int lg = sg ^ (row & 7);
            kr[s] = *(const bf16x8*)(kh + (size_t)(kv1 + row) * DH + lg * 8);
            vr[s] = *(const bf16x8*)(vh + (size_t)row * SEQ + kv1 + lg * 8);
        }
    }
    __syncthreads();

    for (int jt = jt0; jt < jt_end; ++jt) {
        // ---- S^T = K * Q^T ----
        const char* Kb = (const char*)Ks;
        const char* Vb = (const char*)Vs;
        float s4[2][4][4];                 // [a][t][r], kv = jt*64+t*16+g*4+r
        #pragma unroll
        for (int t = 0; t < 4; ++t) {
            f32x4 sa0 = {}, sa1 = {};
            #pragma unroll
            for (int c = 0; c < 2; ++c) {
                bf16x8 kf = *(const bf16x8*)(Kb +
                    (t * 16 + li) * 128 + (((c * 4 + g) ^ (li & 7)) << 4));
                sa0 = __builtin_amdgcn_mfma_f32_16x16x32_bf16(kf, qf[0][c], sa0, 0, 0, 0);
                sa1 = __builtin_amdgcn_mfma_f32_16x16x32_bf16(kf, qf[1][c], sa1, 0, 0, 0);
            }
            #pragma unroll
            for (int r = 0; r < 4; ++r) { s4[0][t][r] = sa0[r]; s4[1][t][r] = sa1[r]; }
        }

        if (jt >= 2 * mt2) {               // diagonal region: causal mask
            #pragma unroll
            for (int a = 0; a < 2; ++a) {
                const int qr = q0 + w * 32 + a * 16 + li;
                #pragma unroll
                for (int t = 0; t < 4; ++t) {
                    #pragma unroll
                    for (int r = 0; r < 4; ++r)
                        if (jt * 64 + t * 16 + g * 4 + r > qr) s4[a][t][r] = -1e30f;
                }
            }
        }

        // ---- p = 2^s -> packed b64 stores (wave-private Ps, no barrier) ----
        #pragma unroll
        for (int a = 0; a < 2; ++a) {
            const int row = a * 16 + li;
            #pragma unroll
            for (int t = 0; t < 4; ++t) {
                bf16x4 p4;
                #pragma unroll
                for (int r = 0; r < 4; ++r) p4[r] = (__bf16)EXP2F(s4[a][t][r]);
                const int pg = (t * 2 + (g >> 1)) ^ (li & 7);
                *(bf16x4*)((char*)Ps + w * 4096 + row * 128 + (pg << 4) + ((g & 1) << 3)) = p4;
            }
        }

        // ---- O += P V ; l += P * ones (pf as A-operand) ----
        #pragma unroll
        for (int c = 0; c < 2; ++c) {
            const int pgp = ((c * 4 + g) ^ (li & 7)) << 4;
            bf16x8 pf0 = *(const bf16x8*)((const char*)Ps + w * 4096 + li * 128 + pgp);
            bf16x8 pf1 = *(const bf16x8*)((const char*)Ps + w * 4096 + (16 + li) * 128 + pgp);
            accl[0] = __builtin_amdgcn_mfma_f32_16x16x32_bf16(pf0, ones, accl[0], 0, 0, 0);
            accl[1] = __builtin_amdgcn_mfma_f32_16x16x32_bf16(pf1, ones, accl[1], 0, 0, 0);
            #pragma unroll
            for (int t = 0; t < 4; ++t) {
                bf16x8 vf = *(const bf16x8*)(Vb + (t * 16 + li) * 128 + pgp);
                acc[0][t] = __builtin_amdgcn_mfma_f32_16x16x32_bf16(pf0, vf, acc[0][t], 0, 0, 0);
                acc[1][t] = __builtin_amdgcn_mfma_f32_16x16x32_bf16(pf1, vf, acc[1][t], 0, 0, 0);
            }
        }

        // ---- single-buffer swap: commit next tile, issue tile after next ----
        if (jt + 1 < jt_end) {
            __syncthreads();               // all waves done reading Ks/Vs
            #pragma unroll
            for (int s = 0; s < 2; ++s) {
                *(bf16x8*)((char*)Ks + s * 4096 + tid * 16) = kr[s];
                *(bf16x8*)((char*)Vs + s * 4096 + tid * 16) = vr[s];
            }
            if (jt + 2 < jt_end) {
                const int kv2 = (jt + 2) * BN;
                #pragma unroll
                for (int s = 0; s < 2; ++s) {
                    const int row = s * 32 + srow0;
                    const int lg = sg ^ (row & 7);
                    kr[s] = *(const bf16x8*)(kh + (size_t)(kv2 + row) * DH + lg * 8);
                    vr[s] = *(const bf16x8*)(vh + (size_t)row * SEQ + kv2 + lg * 8);
                }
            }
            __syncthreads();               // commit visible before next reads
        }
    }

    if (2 * mt2 + 2 <= 6) {
        // ---- single-chunk q-tile: normalize in-register, write out directly
        float* oh = out + (size_t)bh * SEQ * DH;
        #pragma unroll
        for (int a = 0; a < 2; ++a) {
            #pragma unroll
            for (int r = 0; r < 4; ++r) {
                const int row = q0 + w * 32 + a * 16 + g * 4 + r;
                const float inv = 1.0f / accl[a][r];
                float* op = oh + (size_t)row * DH + li;
                #pragma unroll
                for (int t = 0; t < 4; ++t) op[t * 16] = acc[a][t][r] * inv;
            }
        }
    } else {
        // ---- partials out (O in bf16; l in f32) ----
        const int slot = (bh * 16 + mt2) * 6 + ch;
        __bf16* po = opart + (size_t)slot * 8192;
        #pragma unroll
        for (int a = 0; a < 2; ++a) {
            #pragma unroll
            for (int r = 0; r < 4; ++r) {
                const int row = w * 32 + a * 16 + g * 4 + r;
                __bf16* op = po + row * 64 + li;
                #pragma unroll
                for (int t = 0; t < 4; ++t) op[t * 16] = (__bf16)acc[a][t][r];
                if (li == 0) lpart[(size_t)slot * 128 + row] = accl[a][r];
            }
        }
    }
}

// ---------------- reduce: sum bf16 chunks, normalize (mt2 >= 3) ----------------
__global__ __launch_bounds__(256)
void fa_reduce(const __bf16* __restrict__ opart, const float* __restrict__ lpart,
               float* __restrict__ out)
{
    const int bx = blockIdx.x;             // 312 = 8 XCDs x 3 headgrp x 13
    const int xcd = bx & 7;
    const int r2 = bx >> 3;                // 0..38
    const int bh = (r2 / 13) * 8 + xcd;    // co-locate with producer XCD
    const int mt2 = 3 + (r2 % 13);
    const int nc = (2 * mt2 + 7) / 6;      // ceil((2*mt2+2)/6)
    const int base = (bh * 16 + mt2) * 6;
    const int tid = threadIdx.x;
    #pragma unroll
    for (int rnd = 0; rnd < 8; ++rnd) {
        const int flat = rnd * 1024 + tid * 4;
        const int row = flat >> 6;
        float o0 = 0, o1 = 0, o2 = 0, o3 = 0, l = 0;
        for (int c = 0; c < nc; ++c) {
            bf16x4 ov = *(const bf16x4*)(opart + (size_t)(base + c) * 8192 + flat);
            o0 += (float)ov[0]; o1 += (float)ov[1]; o2 += (float)ov[2]; o3 += (float)ov[3];
            l += lpart[(size_t)(base + c) * 128 + row];
        }
        const float inv = 1.0f / l;
        f32x4 res = { o0 * inv, o1 * inv, o2 * inv, o3 * inv };
        *(f32x4*)(out + (size_t)bh * SEQ * DH + (size_t)mt2 * 8192 + flat) = res;
    }
}

// ---------------- fallback: R1 self-contained kernel ----------------
__global__ __launch_bounds__(256, 2)
void fa_causal_kernel(const float* __restrict__ q, const float* __restrict__ k,
                      const float* __restrict__ v, float* __restrict__ out)
{
    const int mt = 31 - (blockIdx.x & 31);
    const int bh = blockIdx.x >> 5;
    const int tid = threadIdx.x;
    const int w = tid >> 6, lane = tid & 63;
    const int g = lane >> 4, li = lane & 15;
    const int m0 = mt * 64;
    __shared__ __bf16 KsF[BN][LDK];
    __shared__ __bf16 VsF[DH][LDK];
    __shared__ __bf16 PsF[4][16][LDK];
    const size_t head_off = (size_t)bh * SEQ * DH;
    const float* qh = q + head_off;
    const float* kh = k + head_off;
    const float* vh = v + head_off;
    float* oh = out + head_off;
    const int qrow = m0 + w * 16 + li;
    bf16x8 qf[2];
    {
        const float* qp = qh + (size_t)qrow * DH + g * 8;
        #pragma unroll
        for (int c = 0; c < 2; ++c) {
            const float* p = qp + c * 32;
            #pragma unroll
            for (int jj = 0; jj < 8; ++jj) qf[c][jj] = (__bf16)p[jj];
        }
    }
    f32x4 acc[4] = {};
    float mrow[4], lrow[4];
    #pragma unroll
    for (int r = 0; r < 4; ++r) { mrow[r] = -1e30f; lrow[r] = 0.0f; }
    const float scale = 0.125f;
    const int srow = tid >> 2, scol = (tid & 3) * 16;
    for (int jt = 0; jt <= mt; ++jt) {
        const int kv0 = jt * BN;
        __syncthreads();
        {
            const float* kp = kh + (size_t)(kv0 + srow) * DH + scol;
            __bf16 tmp[16];
            #pragma unroll
            for (int jj = 0; jj < 16; ++jj) tmp[jj] = (__bf16)kp[jj];
            *(bf16x8*)&KsF[srow][scol]     = *(bf16x8*)&tmp[0];
            *(bf16x8*)&KsF[srow][scol + 8] = *(bf16x8*)&tmp[8];
            const float* vp = vh + (size_t)(kv0 + srow) * DH + scol;
            #pragma unroll
            for (int jj = 0; jj < 16; ++jj) VsF[scol + jj][srow] = (__bf16)vp[jj];
        }
        __syncthreads();
        float s4[4][4];
        #pragma unroll
        for (int t = 0; t < 4; ++t) {
            f32x4 sa = {};
            #pragma unroll
            for (int c = 0; c < 2; ++c) {
                bf16x8 kfr = *(const bf16x8*)&KsF[t * 16 + li][c * 32 + g * 8];
                sa = __builtin_amdgcn_mfma_f32_16x16x32_bf16(qf[c], kfr, sa, 0, 0, 0);
            }
            #pragma unroll
            for (int r = 0; r < 4; ++r) s4[t][r] = sa[r] * scale;
        }
        if (jt == mt) {
            #pragma unroll
            for (int t = 0; t < 4; ++t) {
                const int col = kv0 + t * 16 + li;
                #pragma unroll
                for (int r = 0; r < 4; ++r)
                    if (col > m0 + w * 16 + g * 4 + r) s4[t][r] = -1e30f;
            }
        }
        #pragma unroll
        for (int r = 0; r < 4; ++r) {
            float mx = fmaxf(fmaxf(s4[0][r], s4[1][r]), fmaxf(s4[2][r], s4[3][r]));
            #pragma unroll
            for (int off = 1; off < 16; off <<= 1)
                mx = fmaxf(mx, __shfl_xor(mx, off, 64));
            const float mnew = fmaxf(mrow[r], mx);
            const float alpha = __expf(mrow[r] - mnew);
            mrow[r] = mnew;
            float ps = 0.0f;
            #pragma unroll
            for (int t = 0; t < 4; ++t) {
                const float p = __expf(s4[t][r] - mnew);
                s4[t][r] = p;
                ps += p;
            }
            #pragma unroll
            for (int off = 1; off < 16; off <<= 1)
                ps += __shfl_xor(ps, off, 64);
            lrow[r] = lrow[r] * alpha + ps;
            #pragma unroll
            for (int t = 0; t < 4; ++t) acc[t][r] *= alpha;
        }
        #pragma unroll
        for (int t = 0; t < 4; ++t)
            #pragma unroll
            for (int r = 0; r < 4; ++r)
                PsF[w][g * 4 + r][t * 16 + li] = (__bf16)s4[t][r];
        __syncthreads();
        #pragma unroll
        for (int c = 0; c < 2; ++c) {
            bf16x8 pf = *(const bf16x8*)&PsF[w][li][c * 32 + g * 8];
            #pragma unroll
            for (int t = 0; t < 4; ++t) {
                bf16x8 vfr = *(const bf16x8*)&VsF[t * 16 + li][c * 32 + g * 8];
                acc[t] = __builtin_amdgcn_mfma_f32_16x16x32_bf16(pf, vfr, acc[t], 0, 0, 0);
            }
        }
    }
    #pragma unroll
    for (int r = 0; r < 4; ++r) {
        const int row = m0 + w * 16 + g * 4 + r;
        const float inv = 1.0f / lrow[r];
        float* op = oh + (size_t)row * DH + li;
        #pragma unroll
        for (int t = 0; t < 4; ++t) op[t * 16] = acc[t][r] * inv;
    }
}

extern "C" void kernel_launch(void* const* d_in, const int* in_sizes, int n_in,
                              void* d_out, int out_size, void* d_ws, size_t ws_size,
                              hipStream_t stream) {
    (void)in_sizes; (void)n_in; (void)out_size;
    const float* q = (const float*)d_in[0];
    const float* k = (const float*)d_in[1];
    const float* v = (const float*)d_in[2];
    float* out = (float*)d_out;

    if (ws_size >= WS_FA12) {
        __bf16* ks = (__bf16*)d_ws;
        __bf16* vt = ks + ELEMS_PER_TENSOR;
        __bf16* opart = (__bf16*)((char*)d_ws + WS_KV);
        float* lpart = (float*)((char*)d_ws + WS_KV + (size_t)NSLOT12 * 8192 * 2);
        prep_kernel<<<dim3(1536 + 768), dim3(256), 0, stream>>>(k, v, ks, vt);
        fa12_kernel<<<dim3(1224), dim3(256), 0, stream>>>(q, ks, vt, opart, lpart, out);
        fa_reduce<<<dim3(312), dim3(256), 0, stream>>>(opart, lpart, out);
    } else {
        fa_causal_kernel<<<dim3(NHEADS * 32), dim3(256), 0, stream>>>(q, k, v, out);
    }
}